// Round 17
// baseline (166.156 us; speedup 1.0000x reference)
//
#include <hip/hip_runtime.h>

typedef unsigned short ushort_t;
typedef unsigned int uint_t;
typedef __attribute__((ext_vector_type(2))) float f32x2;
typedef __attribute__((ext_vector_type(4))) float f32x4;
typedef __attribute__((ext_vector_type(16))) float f32x16;
typedef __attribute__((ext_vector_type(4))) unsigned int u32x4;
typedef __attribute__((ext_vector_type(8))) short short8;

#define R3 32768
#define NPTS 65536

__device__ __forceinline__ float bf_lo(uint_t u) { return __uint_as_float(u << 16); }
__device__ __forceinline__ float bf_hi(uint_t u) { return __uint_as_float(u & 0xffff0000u); }
__device__ __forceinline__ ushort_t f2b(float f) {
    uint_t u = __float_as_uint(f);
    u += 0x7fffu + ((u >> 16) & 1u);
    return (ushort_t)(u >> 16);
}
__device__ __forceinline__ float normc(float c) {
    float v = (c / 1.1f + 1.0f) * 0.5f * 31.0f;
    return fminf(fmaxf(v, 0.0f), 31.0f);
}

// ---------------- pass 1: voxel id + histogram ----------------
__global__ __launch_bounds__(256) void k_vid(const float* __restrict__ coords,
                                             int* __restrict__ vid,
                                             uint_t* __restrict__ hist) {
    int gid = blockIdx.x * 256 + threadIdx.x;
    int b = gid >> 16, n = gid & 65535;
    const float* cp = coords + (size_t)b * 3 * NPTS + n;
    int ix = (int)floorf(normc(cp[0]) + 0.5f);
    int iy = (int)floorf(normc(cp[NPTS]) + 0.5f);
    int iz = (int)floorf(normc(cp[2 * NPTS]) + 0.5f);
    ix = min(max(ix, 0), 31); iy = min(max(iy, 0), 31); iz = min(max(iz, 0), 31);
    int v = b * R3 + ((ix * 32 + iy) * 32 + iz);
    vid[gid] = v;
    atomicAdd(hist + v, 1u);
}

// ---------------- scan stage A: per-1024-bin blocks ----------------
__global__ __launch_bounds__(256) void k_scanA(const uint_t* __restrict__ hist,
                                               uint_t* __restrict__ excl,
                                               uint_t* __restrict__ bsum) {
    __shared__ uint_t sh[256];
    int t = threadIdx.x;
    int base = blockIdx.x * 1024 + t * 4;
    uint_t v0 = hist[base], v1 = hist[base + 1], v2 = hist[base + 2], v3 = hist[base + 3];
    uint_t s = v0 + v1 + v2 + v3;
    sh[t] = s;
    __syncthreads();
    uint_t x = s;
    for (int off = 1; off < 256; off <<= 1) {
        uint_t y = (t >= off) ? sh[t - off] : 0u;
        __syncthreads();
        x += y;
        sh[t] = x;
        __syncthreads();
    }
    uint_t e = x - s;
    excl[base] = e;
    excl[base + 1] = e + v0;
    excl[base + 2] = e + v0 + v1;
    excl[base + 3] = e + v0 + v1 + v2;
    if (t == 255) bsum[blockIdx.x] = x;
}

// ---------------- scan stage C (scanB folded in): add block prefix ----------------
// Each block's 256 bins lie within ONE scanA super-block j = blockIdx>>2, so the
// needed offset is prefix(bsum)[j], computed locally via a 256-wide tree reduce.
__global__ __launch_bounds__(256) void k_scanC(uint_t* __restrict__ excl,
                                               const uint_t* __restrict__ bsum,
                                               uint_t* __restrict__ cursor) {
    __shared__ uint_t sb[256];
    int t = threadIdx.x;
    int j = blockIdx.x >> 2;             // scanA block index (0..127)
    sb[t] = (t < j) ? bsum[t] : 0u;      // t<j<=127 -> valid bsum reads only
    __syncthreads();
#pragma unroll
    for (int off = 128; off >= 1; off >>= 1) {
        if (t < off) sb[t] += sb[t + off];
        __syncthreads();
    }
    uint_t boff = sb[0];
    int i = blockIdx.x * 256 + t;
    uint_t v = excl[i] + boff;
    excl[i] = v;
    cursor[i] = v;
}

// ---------------- pass 2: scatter features into voxel-sorted records ----------------
__global__ __launch_bounds__(256) void k_scatfeat(const float* __restrict__ feat,
                                                  const int* __restrict__ vid,
                                                  uint_t* __restrict__ cursor,
                                                  ushort_t* __restrict__ sorted) {
    int gid = blockIdx.x * 256 + threadIdx.x;
    int b = gid >> 16, n = gid & 65535;
    int v = vid[gid];
    uint_t slot = atomicAdd(cursor + v, 1u);
    const float* f = feat + (size_t)b * 32 * NPTS + n;
    ushort_t* dst = sorted + (size_t)slot * 32;
#pragma unroll
    for (int q = 0; q < 4; ++q) {
        u32x4 val;
#pragma unroll
        for (int j = 0; j < 4; ++j) {
            float a = f[(size_t)(q * 8 + j * 2) * NPTS];
            float c = f[(size_t)(q * 8 + j * 2 + 1) * NPTS];
            val[j] = (uint_t)f2b(a) | ((uint_t)f2b(c) << 16);
        }
        *(u32x4*)(dst + q * 8) = val;
    }
}

// ---------------- pass 3: per-voxel contiguous reduce -> bf16 mean ----------------
__global__ __launch_bounds__(256) void k_reduce(const ushort_t* __restrict__ sorted,
                                                const uint_t* __restrict__ start,
                                                const uint_t* __restrict__ hist,
                                                ushort_t* __restrict__ mean_cl) {
    int v = blockIdx.x * 256 + threadIdx.x;
    uint_t s = start[v], c = hist[v];
    float acc[32];
#pragma unroll
    for (int i = 0; i < 32; ++i) acc[i] = 0.0f;
    for (uint_t i = 0; i < c; ++i) {
        const u32x4* p = (const u32x4*)(sorted + (size_t)(s + i) * 32);
#pragma unroll
        for (int q = 0; q < 4; ++q) {
            u32x4 val = p[q];
#pragma unroll
            for (int j = 0; j < 4; ++j) {
                acc[q * 8 + j * 2] += bf_lo(val[j]);
                acc[q * 8 + j * 2 + 1] += bf_hi(val[j]);
            }
        }
    }
    float inv = 1.0f / fmaxf((float)c, 1.0f);
    ushort_t* dst = mean_cl + (size_t)v * 32;
#pragma unroll
    for (int q = 0; q < 4; ++q) {
        u32x4 val;
#pragma unroll
        for (int j = 0; j < 4; ++j)
            val[j] = (uint_t)f2b(acc[q * 8 + j * 2] * inv) |
                     ((uint_t)f2b(acc[q * 8 + j * 2 + 1] * inv) << 16);
        *(u32x4*)(dst + q * 8) = val;
    }
}

// ---------------- weight repack + hist zero (replaces slow hipMemsetAsync) ----------------
__global__ __launch_bounds__(256) void k_wpack(const float* __restrict__ w1,
                                               const float* __restrict__ w2,
                                               ushort_t* __restrict__ Wp1,
                                               ushort_t* __restrict__ Wp2,
                                               uint_t* __restrict__ hist) {
    int t = blockIdx.x * 256 + threadIdx.x;
    if (t < 131072) hist[t] = 0u;         // hist zeroing folded in (runs pre-k_vid)
    if (t < 55296) {                      // conv1: 3 * 36 * 64 * 8
        int dz = t / 18432, r = t % 18432;
        int kb = r >> 9, o = (r >> 3) & 63, ke = r & 7;
        int k = kb * 8 + ke, ci = k & 31, n9 = k >> 5;
        Wp1[t] = f2b(w1[(o * 32 + ci) * 27 + n9 * 3 + dz]);
    } else if (t < 165888) {              // conv2: 3 * 72 * 64 * 8
        int u = t - 55296;
        int dz = u / 36864, r = u % 36864;
        int kb = r >> 9, o = (r >> 3) & 63, ke = r & 7;
        int k = kb * 8 + ke, ci = k & 63, n9 = k >> 6;
        Wp2[u] = f2b(w2[(o * 64 + ci) * 27 + n9 * 3 + dz]);
    }
}

// ---------------- 3x3x3 conv: 32x32x16 MFMA, M=128 (8y x 16z), N=64 ----------------
// Exact R11 structure (best): single T buffer, T14 async-STAGE reg split,
// S stride 133, natural block order.
template <int CB, bool WRITE_CF>
__global__ __launch_bounds__(256, 4) void k_conv(const ushort_t* __restrict__ in_b16,
                                                 const ushort_t* __restrict__ Wp,
                                                 const float* __restrict__ bias,
                                                 ushort_t* __restrict__ out_cl,
                                                 float* __restrict__ out_cf) {
    constexpr int CI = CB * 8;
    constexpr int CHUNKS = CB * 10 * 19;            // 16B chunks per plane
    constexpr int CPW = (CHUNKS + 255) / 256;       // chunks per thread
    constexpr int CHUNKS_PAD = CPW * 256;
    __shared__ union ShU {
        ushort_t T[CHUNKS_PAD * 8];     // chunk c at T[c*8]: c=(cb*10+yy)*19+zz
        float S[64][133];               // [o][m] transpose staging (stride 5 mod 32)
    } sh;
    int tid = threadIdx.x, bid = blockIdx.x;
    int zh = bid & 1, ys = (bid >> 1) & 3, x = (bid >> 3) & 31, b = bid >> 8;
    int y0 = ys * 8, z0 = zh * 16;
    int lane = tid & 63, wv = tid >> 6;

    // per-lane staging sources (dx-independent part), computed once
    int soff[CPW];
    bool vld[CPW];
#pragma unroll
    for (int i = 0; i < CPW; ++i) {
        int c = (wv * CPW + i) * 64 + lane;
        int zz = c % 19, t1 = c / 19, yy = t1 % 10, cb = t1 / 10;
        int gy = y0 + yy - 1, gz = z0 + zz - 1;
        vld[i] = (c < CHUNKS) & ((unsigned)gy < 32u) & ((unsigned)gz < 32u);
        soff[i] = (gy * 32 + gz) * CI + cb * 8;
    }
    const ushort_t* inb = in_b16 + (size_t)b * R3 * CI;

    u32x4 sreg[CPW];
    auto stage_load = [&](int dx) {       // global -> regs (issue early)
        int gx = x + dx - 1;
        bool xok = (unsigned)gx < 32u;
        const ushort_t* base = inb + (size_t)gx * (1024 * CI);
#pragma unroll
        for (int i = 0; i < CPW; ++i) {
            u32x4 z4 = {0u, 0u, 0u, 0u};
            sreg[i] = (xok && vld[i]) ? *(const u32x4*)(base + soff[i]) : z4;
        }
    };
    auto stage_write = [&]() {            // regs -> LDS (after barrier)
#pragma unroll
        for (int i = 0; i < CPW; ++i)
            *(u32x4*)(&sh.T[((wv * CPW + i) * 64 + lane) * 8]) = sreg[i];
    };

    int nq = wv & 1, mq = wv >> 1;
    int l31 = lane & 31, lh = lane >> 5;
    int o = nq * 32 + l31;
    int ya0 = mq * 4 + (l31 >> 4);       // (row>>4) for msub = 2*mq
    int ya1 = ya0 + 2;                   // msub = 2*mq+1
    int za = l31 & 15;

    f32x16 acc0, acc1;
#pragma unroll
    for (int i = 0; i < 16; ++i) { acc0[i] = 0.0f; acc1[i] = 0.0f; }

    stage_load(0);
    stage_write();
    __syncthreads();
#pragma unroll
    for (int dx = 0; dx < 3; ++dx) {
        if (dx < 2) stage_load(dx + 1);   // async loads overlap the MFMA phase
        const ushort_t* Tp = &sh.T[0];
        const ushort_t* wpB = Wp + (size_t)o * 8;
#pragma unroll
        for (int dz = 0; dz < 3; ++dz)
#pragma unroll
            for (int dy = 0; dy < 3; ++dy)
#pragma unroll
                for (int cbp = 0; cbp < CB / 2; ++cbp) {
                    int cb = cbp * 2 + lh;
                    const ushort_t* tb = Tp + (size_t)cb * (10 * 19 * 8);
                    short8 a0 = *(const short8*)(tb + ((ya0 + dy) * 19 + za + dz) * 8);
                    short8 a1 = *(const short8*)(tb + ((ya1 + dy) * 19 + za + dz) * 8);
                    int kb = (dx * 3 + dy) * CB + cb;
                    short8 bw = *(const short8*)(wpB + (size_t)(dz * 9 * CB + kb) * 512);
                    acc0 = __builtin_amdgcn_mfma_f32_32x32x16_bf16(a0, bw, acc0, 0, 0, 0);
                    acc1 = __builtin_amdgcn_mfma_f32_32x32x16_bf16(a1, bw, acc1, 0, 0, 0);
                }
        __syncthreads();                  // all reads of T done
        if (dx < 2) {
            stage_write();                // overwrite T in place
            __syncthreads();              // staged data visible
        }
    }

    // epilogue: bias + leaky, transpose via S[o][m]
    float bia = bias[o];
#pragma unroll
    for (int i = 0; i < 2; ++i) {
        int mbase = (mq * 2 + i) * 32 + lh * 4;
#pragma unroll
        for (int rq = 0; rq < 4; ++rq) {
            f32x4 v4;
#pragma unroll
            for (int j = 0; j < 4; ++j) {
                float v = (i ? acc1[rq * 4 + j] : acc0[rq * 4 + j]) + bia;
                v4[j] = (v >= 0.0f) ? v : 0.1f * v;
            }
            *(f32x4*)(&sh.S[o][mbase + rq * 8]) = v4;
        }
    }
    __syncthreads();

    // channel-last bf16 out: thread -> (voxel, o-half)
    {
        int vl = tid >> 1, oh = tid & 1;
        int y = vl >> 4, z = vl & 15;
        ushort_t* dst =
            out_cl + ((size_t)(b * R3 + x * 1024 + (y0 + y) * 32 + z0 + z)) * 64 + oh * 32;
#pragma unroll
        for (int q = 0; q < 4; ++q) {
            u32x4 w;
#pragma unroll
            for (int j4 = 0; j4 < 4; ++j4) {
                int oo = oh * 32 + q * 8 + j4 * 2;
                w[j4] = (uint_t)f2b(sh.S[oo][vl]) | ((uint_t)f2b(sh.S[oo + 1][vl]) << 16);
            }
            *(u32x4*)(dst + q * 8) = w;
        }
    }
    if (WRITE_CF) {
        // channel-first f32 out: thread -> (o, z-quad), loop y
        int oo = tid >> 2, zq = tid & 3;
        float* dp = out_cf + (size_t)(b * 64 + oo) * R3 + x * 1024 + y0 * 32 + z0 + zq * 4;
#pragma unroll
        for (int y = 0; y < 8; ++y)
            *(f32x4*)(dp + y * 32) = *(const f32x4*)(&sh.S[oo][y * 16 + zq * 4]);
    }
}

// ---------------- MLP + trilinear sample + add (wave-coalesced) ----------------
__global__ __launch_bounds__(256) void k_point(const float* __restrict__ feat,
                                               const float* __restrict__ coords,
                                               const float* __restrict__ w_mlp,
                                               const float* __restrict__ b_mlp,
                                               const ushort_t* __restrict__ vf,
                                               float* __restrict__ out) {
    __shared__ int vox_s[64][8];
    __shared__ float wgt_s[64][8];
    __shared__ float S[64][65];
    int tid = threadIdx.x;
    int b = blockIdx.x >> 10;
    int p0 = (blockIdx.x & 1023) * 64;
    int lane = tid & 63, wv = tid >> 6;

    // prefetch Phase-B feat row early (independent of LDS phases)
    const float* fb = feat + (size_t)b * 32 * NPTS + p0 + lane;
    float ft[32];
#pragma unroll
    for (int ci = 0; ci < 32; ++ci) ft[ci] = fb[(size_t)ci * NPTS];

    {
        int p = tid & 63, cpair = tid >> 6;
        const float* cp = coords + (size_t)b * 3 * NPTS + p0 + p;
        float nx = normc(cp[0]), ny = normc(cp[NPTS]), nz = normc(cp[2 * NPTS]);
        int x0 = min(max((int)floorf(nx), 0), 31);
        int y0 = min(max((int)floorf(ny), 0), 31);
        int z0 = min(max((int)floorf(nz), 0), 31);
        float fx = nx - (float)x0, fy = ny - (float)y0, fz = nz - (float)z0;
        int x1 = min(x0 + 1, 31), y1 = min(y0 + 1, 31), z1 = min(z0 + 1, 31);
#pragma unroll
        for (int j = 0; j < 2; ++j) {
            int c = cpair * 2 + j;
            int xi = (c & 4) ? x1 : x0, yi = (c & 2) ? y1 : y0, zi = (c & 1) ? z1 : z0;
            float wc = ((c & 4) ? fx : 1.0f - fx) * ((c & 2) ? fy : 1.0f - fy) *
                       ((c & 1) ? fz : 1.0f - fz);
            vox_s[p][c] = (xi * 32 + yi) * 32 + zi;
            wgt_s[p][c] = wc;
        }
    }
    __syncthreads();

    // Phase A: 2 points per iter; half-wave = point, lane = 2 channels (u32)
    {
        int l5 = lane & 31, lh2 = lane >> 5;
        const ushort_t* vfb = vf + (size_t)b * R3 * 64 + 2 * l5;
        for (int t = 0; t < 8; ++t) {
            int p = wv * 16 + t * 2 + lh2;
            float s0 = 0.0f, s1 = 0.0f;
#pragma unroll
            for (int c = 0; c < 8; ++c) {
                int vox = vox_s[p][c];
                float wc = wgt_s[p][c];
                uint_t raw = *(const uint_t*)(vfb + (size_t)vox * 64);
                s0 = fmaf(wc, bf_lo(raw), s0);
                s1 = fmaf(wc, bf_hi(raw), s1);
            }
            f32x2 sv = {s0, s1};
            *(f32x2*)(&S[p][2 * l5]) = sv;
        }
    }
    __syncthreads();

    // Phase B: lane = point, wave handles 16 output channels
    {
        int o0 = __builtin_amdgcn_readfirstlane(wv) * 16;
        float* ob = out + ((size_t)b * 64 + o0) * NPTS + p0 + lane;
#pragma unroll
        for (int oi = 0; oi < 16; ++oi) {
            float m = b_mlp[o0 + oi];
            const float* wrow = w_mlp + (size_t)(o0 + oi) * 32;
#pragma unroll
            for (int ci = 0; ci < 32; ++ci) m = fmaf(wrow[ci], ft[ci], m);
            m = fmaxf(m, 0.0f);
            ob[(size_t)oi * NPTS] = m + S[lane][o0 + oi];
        }
    }
}

extern "C" void kernel_launch(void* const* d_in, const int* in_sizes, int n_in,
                              void* d_out, int out_size, void* d_ws, size_t ws_size,
                              hipStream_t stream) {
    const float* feat   = (const float*)d_in[0];
    const float* coords = (const float*)d_in[1];
    const float* w_mlp  = (const float*)d_in[2];
    const float* b_mlp  = (const float*)d_in[3];
    const float* w_c1   = (const float*)d_in[4];
    const float* b_c1   = (const float*)d_in[5];
    const float* w_c2   = (const float*)d_in[6];
    const float* b_c2   = (const float*)d_in[7];

    float* out = (float*)d_out;
    float* point_out = out;                 // [4][64][65536] f32 (final)
    float* vfeat = out + 16777216;          // [4][64][32768] f32 (final)

    // scratch overlaid on the point_out region (only k_point, last, writes it)
    ushort_t* sorted  = (ushort_t*)out;                   // [262144][32] bf16
    ushort_t* mean_cl = (ushort_t*)(out + 4194304);       // [131072][32] bf16
    ushort_t* v_cl    = (ushort_t*)(out + 6291456);       // [131072][64] bf16
    int*      vid     = (int*)(out + 10485760);           // [262144]
    uint_t*   hist    = (uint_t*)(out + 10747904);        // [131072]
    uint_t*   excl    = (uint_t*)(out + 10878976);        // [131072]
    uint_t*   cursor  = (uint_t*)(out + 11010048);        // [131072]
    uint_t*   bsum    = (uint_t*)(out + 11141120);        // [128]
    ushort_t* Wp1     = (ushort_t*)(out + 11141376);      // [55296] bf16
    ushort_t* Wp2     = (ushort_t*)(out + 11169024);      // [110592] bf16
    ushort_t* vf_cl   = (ushort_t*)d_ws;                  // [131072][64] bf16

    k_wpack<<<648, 256, 0, stream>>>(w_c1, w_c2, Wp1, Wp2, hist);
    k_vid<<<1024, 256, 0, stream>>>(coords, vid, hist);
    k_scanA<<<128, 256, 0, stream>>>(hist, excl, bsum);
    k_scanC<<<512, 256, 0, stream>>>(excl, bsum, cursor);
    k_scatfeat<<<1024, 256, 0, stream>>>(feat, vid, cursor, sorted);
    k_reduce<<<512, 256, 0, stream>>>(sorted, excl, hist, mean_cl);
    k_conv<4, false><<<1024, 256, 0, stream>>>(mean_cl, Wp1, b_c1, v_cl, (float*)nullptr);
    k_conv<8, true><<<1024, 256, 0, stream>>>(v_cl, Wp2, b_c2, vf_cl, vfeat);
    k_point<<<4096, 256, 0, stream>>>(feat, coords, w_mlp, b_mlp, vf_cl, point_out);
}

// Round 18
// 163.327 us; speedup vs baseline: 1.0173x; 1.0173x over previous
//
#include <hip/hip_runtime.h>

typedef unsigned short ushort_t;
typedef unsigned int uint_t;
typedef __attribute__((ext_vector_type(2))) float f32x2;
typedef __attribute__((ext_vector_type(4))) float f32x4;
typedef __attribute__((ext_vector_type(16))) float f32x16;
typedef __attribute__((ext_vector_type(4))) unsigned int u32x4;
typedef __attribute__((ext_vector_type(8))) short short8;

#define R3 32768
#define NPTS 65536

__device__ __forceinline__ float bf_lo(uint_t u) { return __uint_as_float(u << 16); }
__device__ __forceinline__ float bf_hi(uint_t u) { return __uint_as_float(u & 0xffff0000u); }
__device__ __forceinline__ ushort_t f2b(float f) {
    uint_t u = __float_as_uint(f);
    u += 0x7fffu + ((u >> 16) & 1u);
    return (ushort_t)(u >> 16);
}
__device__ __forceinline__ float normc(float c) {
    float v = (c / 1.1f + 1.0f) * 0.5f * 31.0f;
    return fminf(fmaxf(v, 0.0f), 31.0f);
}

// ---------------- pass 1: voxel id + histogram ----------------
__global__ __launch_bounds__(256) void k_vid(const float* __restrict__ coords,
                                             int* __restrict__ vid,
                                             uint_t* __restrict__ hist) {
    int gid = blockIdx.x * 256 + threadIdx.x;
    int b = gid >> 16, n = gid & 65535;
    const float* cp = coords + (size_t)b * 3 * NPTS + n;
    int ix = (int)floorf(normc(cp[0]) + 0.5f);
    int iy = (int)floorf(normc(cp[NPTS]) + 0.5f);
    int iz = (int)floorf(normc(cp[2 * NPTS]) + 0.5f);
    ix = min(max(ix, 0), 31); iy = min(max(iy, 0), 31); iz = min(max(iz, 0), 31);
    int v = b * R3 + ((ix * 32 + iy) * 32 + iz);
    vid[gid] = v;
    atomicAdd(hist + v, 1u);
}

// ---------------- exclusive scan over 131072 bins (3 kernels) ----------------
__global__ __launch_bounds__(256) void k_scanA(const uint_t* __restrict__ hist,
                                               uint_t* __restrict__ excl,
                                               uint_t* __restrict__ bsum) {
    __shared__ uint_t sh[256];
    int t = threadIdx.x;
    int base = blockIdx.x * 1024 + t * 4;
    uint_t v0 = hist[base], v1 = hist[base + 1], v2 = hist[base + 2], v3 = hist[base + 3];
    uint_t s = v0 + v1 + v2 + v3;
    sh[t] = s;
    __syncthreads();
    uint_t x = s;
    for (int off = 1; off < 256; off <<= 1) {
        uint_t y = (t >= off) ? sh[t - off] : 0u;
        __syncthreads();
        x += y;
        sh[t] = x;
        __syncthreads();
    }
    uint_t e = x - s;
    excl[base] = e;
    excl[base + 1] = e + v0;
    excl[base + 2] = e + v0 + v1;
    excl[base + 3] = e + v0 + v1 + v2;
    if (t == 255) bsum[blockIdx.x] = x;
}

__global__ __launch_bounds__(128) void k_scanB(uint_t* __restrict__ bsum,
                                               uint_t* __restrict__ boff) {
    __shared__ uint_t sh[128];
    int t = threadIdx.x;
    uint_t s = bsum[t];
    sh[t] = s;
    __syncthreads();
    uint_t x = s;
    for (int off = 1; off < 128; off <<= 1) {
        uint_t y = (t >= off) ? sh[t - off] : 0u;
        __syncthreads();
        x += y;
        sh[t] = x;
        __syncthreads();
    }
    boff[t] = x - s;
}

__global__ __launch_bounds__(256) void k_scanC(uint_t* __restrict__ excl,
                                               const uint_t* __restrict__ boff,
                                               uint_t* __restrict__ cursor) {
    int i = blockIdx.x * 256 + threadIdx.x;
    uint_t v = excl[i] + boff[i >> 10];
    excl[i] = v;
    cursor[i] = v;
}

// ---------------- pass 2: scatter features into voxel-sorted records ----------------
__global__ __launch_bounds__(256) void k_scatfeat(const float* __restrict__ feat,
                                                  const int* __restrict__ vid,
                                                  uint_t* __restrict__ cursor,
                                                  ushort_t* __restrict__ sorted) {
    int gid = blockIdx.x * 256 + threadIdx.x;
    int b = gid >> 16, n = gid & 65535;
    int v = vid[gid];
    uint_t slot = atomicAdd(cursor + v, 1u);
    const float* f = feat + (size_t)b * 32 * NPTS + n;
    ushort_t* dst = sorted + (size_t)slot * 32;
#pragma unroll
    for (int q = 0; q < 4; ++q) {
        u32x4 val;
#pragma unroll
        for (int j = 0; j < 4; ++j) {
            float a = f[(size_t)(q * 8 + j * 2) * NPTS];
            float c = f[(size_t)(q * 8 + j * 2 + 1) * NPTS];
            val[j] = (uint_t)f2b(a) | ((uint_t)f2b(c) << 16);
        }
        *(u32x4*)(dst + q * 8) = val;
    }
}

// ---------------- pass 3: per-voxel contiguous reduce -> bf16 mean ----------------
__global__ __launch_bounds__(256) void k_reduce(const ushort_t* __restrict__ sorted,
                                                const uint_t* __restrict__ start,
                                                const uint_t* __restrict__ hist,
                                                ushort_t* __restrict__ mean_cl) {
    int v = blockIdx.x * 256 + threadIdx.x;
    uint_t s = start[v], c = hist[v];
    float acc[32];
#pragma unroll
    for (int i = 0; i < 32; ++i) acc[i] = 0.0f;
    for (uint_t i = 0; i < c; ++i) {
        const u32x4* p = (const u32x4*)(sorted + (size_t)(s + i) * 32);
#pragma unroll
        for (int q = 0; q < 4; ++q) {
            u32x4 val = p[q];
#pragma unroll
            for (int j = 0; j < 4; ++j) {
                acc[q * 8 + j * 2] += bf_lo(val[j]);
                acc[q * 8 + j * 2 + 1] += bf_hi(val[j]);
            }
        }
    }
    float inv = 1.0f / fmaxf((float)c, 1.0f);
    ushort_t* dst = mean_cl + (size_t)v * 32;
#pragma unroll
    for (int q = 0; q < 4; ++q) {
        u32x4 val;
#pragma unroll
        for (int j = 0; j < 4; ++j)
            val[j] = (uint_t)f2b(acc[q * 8 + j * 2] * inv) |
                     ((uint_t)f2b(acc[q * 8 + j * 2 + 1] * inv) << 16);
        *(u32x4*)(dst + q * 8) = val;
    }
}

// ---------------- weight repack + hist zero (replaces slow hipMemsetAsync) ----------------
__global__ __launch_bounds__(256) void k_wpack(const float* __restrict__ w1,
                                               const float* __restrict__ w2,
                                               ushort_t* __restrict__ Wp1,
                                               ushort_t* __restrict__ Wp2,
                                               uint_t* __restrict__ hist) {
    int t = blockIdx.x * 256 + threadIdx.x;
    if (t < 131072) hist[t] = 0u;         // hist zeroing folded in (runs pre-k_vid)
    if (t < 55296) {                      // conv1: 3 * 36 * 64 * 8
        int dz = t / 18432, r = t % 18432;
        int kb = r >> 9, o = (r >> 3) & 63, ke = r & 7;
        int k = kb * 8 + ke, ci = k & 31, n9 = k >> 5;
        Wp1[t] = f2b(w1[(o * 32 + ci) * 27 + n9 * 3 + dz]);
    } else if (t < 165888) {              // conv2: 3 * 72 * 64 * 8
        int u = t - 55296;
        int dz = u / 36864, r = u % 36864;
        int kb = r >> 9, o = (r >> 3) & 63, ke = r & 7;
        int k = kb * 8 + ke, ci = k & 63, n9 = k >> 6;
        Wp2[u] = f2b(w2[(o * 64 + ci) * 27 + n9 * 3 + dz]);
    }
}

// ---------------- 3x3x3 conv: 32x32x16 MFMA, M=128 (8y x 16z), N=64 ----------------
// R11 structure + optional T double-buffer (DBUF): writes go to the other
// buffer DURING the MFMA phase -> one barrier per dx-phase instead of two.
// conv1 (CB=4): dbuf fits inside the S-dominated union (34KB) -> FREE.
// conv2 (CB=8): 2xT=49KB > S -> keep single-T (proven R11 path).
template <int CB, bool WRITE_CF, bool DBUF>
__global__ __launch_bounds__(256, 4) void k_conv(const ushort_t* __restrict__ in_b16,
                                                 const ushort_t* __restrict__ Wp,
                                                 const float* __restrict__ bias,
                                                 ushort_t* __restrict__ out_cl,
                                                 float* __restrict__ out_cf) {
    constexpr int CI = CB * 8;
    constexpr int CHUNKS = CB * 10 * 19;            // 16B chunks per plane
    constexpr int CPW = (CHUNKS + 255) / 256;       // chunks per thread
    constexpr int CHUNKS_PAD = CPW * 256;
    constexpr int NB = DBUF ? 2 : 1;
    __shared__ union ShU {
        ushort_t T[NB][CHUNKS_PAD * 8]; // chunk c at T[pb][c*8]: c=(cb*10+yy)*19+zz
        float S[64][133];               // [o][m] transpose staging (stride 5 mod 32)
    } sh;
    int tid = threadIdx.x, bid = blockIdx.x;
    int zh = bid & 1, ys = (bid >> 1) & 3, x = (bid >> 3) & 31, b = bid >> 8;
    int y0 = ys * 8, z0 = zh * 16;
    int lane = tid & 63, wv = tid >> 6;

    // per-lane staging sources (dx-independent part), computed once
    int soff[CPW];
    bool vld[CPW];
#pragma unroll
    for (int i = 0; i < CPW; ++i) {
        int c = (wv * CPW + i) * 64 + lane;
        int zz = c % 19, t1 = c / 19, yy = t1 % 10, cb = t1 / 10;
        int gy = y0 + yy - 1, gz = z0 + zz - 1;
        vld[i] = (c < CHUNKS) & ((unsigned)gy < 32u) & ((unsigned)gz < 32u);
        soff[i] = (gy * 32 + gz) * CI + cb * 8;
    }
    const ushort_t* inb = in_b16 + (size_t)b * R3 * CI;

    u32x4 sreg[CPW];
    auto stage_load = [&](int dx) {       // global -> regs (issue early)
        int gx = x + dx - 1;
        bool xok = (unsigned)gx < 32u;
        const ushort_t* base = inb + (size_t)gx * (1024 * CI);
#pragma unroll
        for (int i = 0; i < CPW; ++i) {
            u32x4 z4 = {0u, 0u, 0u, 0u};
            sreg[i] = (xok && vld[i]) ? *(const u32x4*)(base + soff[i]) : z4;
        }
    };
    auto stage_write = [&](int pb) {      // regs -> LDS buffer pb
#pragma unroll
        for (int i = 0; i < CPW; ++i)
            *(u32x4*)(&sh.T[pb][((wv * CPW + i) * 64 + lane) * 8]) = sreg[i];
    };

    int nq = wv & 1, mq = wv >> 1;
    int l31 = lane & 31, lh = lane >> 5;
    int o = nq * 32 + l31;
    int ya0 = mq * 4 + (l31 >> 4);       // (row>>4) for msub = 2*mq
    int ya1 = ya0 + 2;                   // msub = 2*mq+1
    int za = l31 & 15;

    f32x16 acc0, acc1;
#pragma unroll
    for (int i = 0; i < 16; ++i) { acc0[i] = 0.0f; acc1[i] = 0.0f; }

    stage_load(0);
    stage_write(0);
    __syncthreads();
#pragma unroll
    for (int dx = 0; dx < 3; ++dx) {
        if (dx < 2) stage_load(dx + 1);   // async loads overlap the MFMA phase
        const ushort_t* Tp = &sh.T[DBUF ? (dx & 1) : 0][0];
        const ushort_t* wpB = Wp + (size_t)o * 8;
#pragma unroll
        for (int dz = 0; dz < 3; ++dz)
#pragma unroll
            for (int dy = 0; dy < 3; ++dy)
#pragma unroll
                for (int cbp = 0; cbp < CB / 2; ++cbp) {
                    int cb = cbp * 2 + lh;
                    const ushort_t* tb = Tp + (size_t)cb * (10 * 19 * 8);
                    short8 a0 = *(const short8*)(tb + ((ya0 + dy) * 19 + za + dz) * 8);
                    short8 a1 = *(const short8*)(tb + ((ya1 + dy) * 19 + za + dz) * 8);
                    int kb = (dx * 3 + dy) * CB + cb;
                    short8 bw = *(const short8*)(wpB + (size_t)(dz * 9 * CB + kb) * 512);
                    acc0 = __builtin_amdgcn_mfma_f32_32x32x16_bf16(a0, bw, acc0, 0, 0, 0);
                    acc1 = __builtin_amdgcn_mfma_f32_32x32x16_bf16(a1, bw, acc1, 0, 0, 0);
                }
        if (DBUF) {
            // write next plane to the OTHER buffer (no one reads it this phase);
            // one barrier: writes visible + everyone done reading T[dx&1]
            if (dx < 2) stage_write((dx + 1) & 1);
            __syncthreads();
        } else {
            __syncthreads();              // all reads of T done
            if (dx < 2) {
                stage_write(0);           // overwrite T in place
                __syncthreads();          // staged data visible
            }
        }
    }

    // epilogue: bias + leaky, transpose via S[o][m]
    float bia = bias[o];
#pragma unroll
    for (int i = 0; i < 2; ++i) {
        int mbase = (mq * 2 + i) * 32 + lh * 4;
#pragma unroll
        for (int rq = 0; rq < 4; ++rq) {
            f32x4 v4;
#pragma unroll
            for (int j = 0; j < 4; ++j) {
                float v = (i ? acc1[rq * 4 + j] : acc0[rq * 4 + j]) + bia;
                v4[j] = (v >= 0.0f) ? v : 0.1f * v;
            }
            *(f32x4*)(&sh.S[o][mbase + rq * 8]) = v4;
        }
    }
    __syncthreads();

    // channel-last bf16 out: thread -> (voxel, o-half)
    {
        int vl = tid >> 1, oh = tid & 1;
        int y = vl >> 4, z = vl & 15;
        ushort_t* dst =
            out_cl + ((size_t)(b * R3 + x * 1024 + (y0 + y) * 32 + z0 + z)) * 64 + oh * 32;
#pragma unroll
        for (int q = 0; q < 4; ++q) {
            u32x4 w;
#pragma unroll
            for (int j4 = 0; j4 < 4; ++j4) {
                int oo = oh * 32 + q * 8 + j4 * 2;
                w[j4] = (uint_t)f2b(sh.S[oo][vl]) | ((uint_t)f2b(sh.S[oo + 1][vl]) << 16);
            }
            *(u32x4*)(dst + q * 8) = w;
        }
    }
    if (WRITE_CF) {
        // channel-first f32 out: thread -> (o, z-quad), loop y
        int oo = tid >> 2, zq = tid & 3;
        float* dp = out_cf + (size_t)(b * 64 + oo) * R3 + x * 1024 + y0 * 32 + z0 + zq * 4;
#pragma unroll
        for (int y = 0; y < 8; ++y)
            *(f32x4*)(dp + y * 32) = *(const f32x4*)(&sh.S[oo][y * 16 + zq * 4]);
    }
}

// ---------------- MLP + trilinear sample + add (wave-coalesced) ----------------
__global__ __launch_bounds__(256) void k_point(const float* __restrict__ feat,
                                               const float* __restrict__ coords,
                                               const float* __restrict__ w_mlp,
                                               const float* __restrict__ b_mlp,
                                               const ushort_t* __restrict__ vf,
                                               float* __restrict__ out) {
    __shared__ int vox_s[64][8];
    __shared__ float wgt_s[64][8];
    __shared__ float S[64][65];
    int tid = threadIdx.x;
    int b = blockIdx.x >> 10;
    int p0 = (blockIdx.x & 1023) * 64;
    int lane = tid & 63, wv = tid >> 6;

    // prefetch Phase-B feat row early (independent of LDS phases)
    const float* fb = feat + (size_t)b * 32 * NPTS + p0 + lane;
    float ft[32];
#pragma unroll
    for (int ci = 0; ci < 32; ++ci) ft[ci] = fb[(size_t)ci * NPTS];

    {
        int p = tid & 63, cpair = tid >> 6;
        const float* cp = coords + (size_t)b * 3 * NPTS + p0 + p;
        float nx = normc(cp[0]), ny = normc(cp[NPTS]), nz = normc(cp[2 * NPTS]);
        int x0 = min(max((int)floorf(nx), 0), 31);
        int y0 = min(max((int)floorf(ny), 0), 31);
        int z0 = min(max((int)floorf(nz), 0), 31);
        float fx = nx - (float)x0, fy = ny - (float)y0, fz = nz - (float)z0;
        int x1 = min(x0 + 1, 31), y1 = min(y0 + 1, 31), z1 = min(z0 + 1, 31);
#pragma unroll
        for (int j = 0; j < 2; ++j) {
            int c = cpair * 2 + j;
            int xi = (c & 4) ? x1 : x0, yi = (c & 2) ? y1 : y0, zi = (c & 1) ? z1 : z0;
            float wc = ((c & 4) ? fx : 1.0f - fx) * ((c & 2) ? fy : 1.0f - fy) *
                       ((c & 1) ? fz : 1.0f - fz);
            vox_s[p][c] = (xi * 32 + yi) * 32 + zi;
            wgt_s[p][c] = wc;
        }
    }
    __syncthreads();

    // Phase A: 2 points per iter; half-wave = point, lane = 2 channels (u32)
    {
        int l5 = lane & 31, lh2 = lane >> 5;
        const ushort_t* vfb = vf + (size_t)b * R3 * 64 + 2 * l5;
        for (int t = 0; t < 8; ++t) {
            int p = wv * 16 + t * 2 + lh2;
            float s0 = 0.0f, s1 = 0.0f;
#pragma unroll
            for (int c = 0; c < 8; ++c) {
                int vox = vox_s[p][c];
                float wc = wgt_s[p][c];
                uint_t raw = *(const uint_t*)(vfb + (size_t)vox * 64);
                s0 = fmaf(wc, bf_lo(raw), s0);
                s1 = fmaf(wc, bf_hi(raw), s1);
            }
            f32x2 sv = {s0, s1};
            *(f32x2*)(&S[p][2 * l5]) = sv;
        }
    }
    __syncthreads();

    // Phase B: lane = point, wave handles 16 output channels
    {
        int o0 = __builtin_amdgcn_readfirstlane(wv) * 16;
        float* ob = out + ((size_t)b * 64 + o0) * NPTS + p0 + lane;
#pragma unroll
        for (int oi = 0; oi < 16; ++oi) {
            float m = b_mlp[o0 + oi];
            const float* wrow = w_mlp + (size_t)(o0 + oi) * 32;
#pragma unroll
            for (int ci = 0; ci < 32; ++ci) m = fmaf(wrow[ci], ft[ci], m);
            m = fmaxf(m, 0.0f);
            ob[(size_t)oi * NPTS] = m + S[lane][o0 + oi];
        }
    }
}

extern "C" void kernel_launch(void* const* d_in, const int* in_sizes, int n_in,
                              void* d_out, int out_size, void* d_ws, size_t ws_size,
                              hipStream_t stream) {
    const float* feat   = (const float*)d_in[0];
    const float* coords = (const float*)d_in[1];
    const float* w_mlp  = (const float*)d_in[2];
    const float* b_mlp  = (const float*)d_in[3];
    const float* w_c1   = (const float*)d_in[4];
    const float* b_c1   = (const float*)d_in[5];
    const float* w_c2   = (const float*)d_in[6];
    const float* b_c2   = (const float*)d_in[7];

    float* out = (float*)d_out;
    float* point_out = out;                 // [4][64][65536] f32 (final)
    float* vfeat = out + 16777216;          // [4][64][32768] f32 (final)

    // scratch overlaid on the point_out region (only k_point, last, writes it)
    ushort_t* sorted  = (ushort_t*)out;                   // [262144][32] bf16
    ushort_t* mean_cl = (ushort_t*)(out + 4194304);       // [131072][32] bf16
    ushort_t* v_cl    = (ushort_t*)(out + 6291456);       // [131072][64] bf16
    int*      vid     = (int*)(out + 10485760);           // [262144]
    uint_t*   hist    = (uint_t*)(out + 10747904);        // [131072]
    uint_t*   excl    = (uint_t*)(out + 10878976);        // [131072]
    uint_t*   cursor  = (uint_t*)(out + 11010048);        // [131072]
    uint_t*   bsum    = (uint_t*)(out + 11141120);        // [128]
    uint_t*   boff    = (uint_t*)(out + 11141248);        // [128]
    ushort_t* Wp1     = (ushort_t*)(out + 11141376);      // [55296] bf16
    ushort_t* Wp2     = (ushort_t*)(out + 11169024);      // [110592] bf16
    ushort_t* vf_cl   = (ushort_t*)d_ws;                  // [131072][64] bf16

    k_wpack<<<648, 256, 0, stream>>>(w_c1, w_c2, Wp1, Wp2, hist);
    k_vid<<<1024, 256, 0, stream>>>(coords, vid, hist);
    k_scanA<<<128, 256, 0, stream>>>(hist, excl, bsum);
    k_scanB<<<1, 128, 0, stream>>>(bsum, boff);
    k_scanC<<<512, 256, 0, stream>>>(excl, boff, cursor);
    k_scatfeat<<<1024, 256, 0, stream>>>(feat, vid, cursor, sorted);
    k_reduce<<<512, 256, 0, stream>>>(sorted, excl, hist, mean_cl);
    k_conv<4, false, true><<<1024, 256, 0, stream>>>(mean_cl, Wp1, b_c1, v_cl,
                                                     (float*)nullptr);
    k_conv<8, true, false><<<1024, 256, 0, stream>>>(v_cl, Wp2, b_c2, vf_cl, vfeat);
    k_point<<<4096, 256, 0, stream>>>(feat, coords, w_mlp, b_mlp, vf_cl, point_out);
}